// Round 1
// baseline (726.029 us; speedup 1.0000x reference)
//
#include <hip/hip_runtime.h>

#define PN 100000

__device__ __forceinline__ unsigned int sortkey(float f) {
    unsigned int u = __float_as_uint(f);
    return u ^ ((u & 0x80000000u) ? 0xFFFFFFFFu : 0x80000000u);
}

// ---------------- K1: angle MLP + row normalize -> ang [256][64] ----------------
__global__ __launch_bounds__(512) void k1_angle_mlp(
    const float* __restrict__ latent,
    const float* __restrict__ aw1, const float* __restrict__ ab1,
    const float* __restrict__ aw2, const float* __restrict__ ab2,
    const float* __restrict__ aw3, const float* __restrict__ ab3,
    const float* __restrict__ aw4, const float* __restrict__ ab4,
    float* __restrict__ ang)
{
    __shared__ __align__(16) float xs[4][256];
    __shared__ __align__(16) float hA[4][512];
    __shared__ __align__(16) float hB[4][512];
    int t = threadIdx.x;
    int b0 = blockIdx.x * 4;
    for (int i = t; i < 4 * 256; i += 512) xs[i >> 8][i & 255] = latent[b0 * 256 + i];
    __syncthreads();
    // L1: [4,256] @ [256,512] -> hA
    {
        float bz = ab1[t];
        float a0 = bz, a1 = bz, a2 = bz, a3 = bz;
        for (int k = 0; k < 256; k += 4) {
            float w0 = aw1[(k + 0) * 512 + t];
            float w1 = aw1[(k + 1) * 512 + t];
            float w2 = aw1[(k + 2) * 512 + t];
            float w3 = aw1[(k + 3) * 512 + t];
            float4 x0 = *(const float4*)&xs[0][k];
            float4 x1 = *(const float4*)&xs[1][k];
            float4 x2 = *(const float4*)&xs[2][k];
            float4 x3 = *(const float4*)&xs[3][k];
            a0 = fmaf(x0.x, w0, a0); a0 = fmaf(x0.y, w1, a0); a0 = fmaf(x0.z, w2, a0); a0 = fmaf(x0.w, w3, a0);
            a1 = fmaf(x1.x, w0, a1); a1 = fmaf(x1.y, w1, a1); a1 = fmaf(x1.z, w2, a1); a1 = fmaf(x1.w, w3, a1);
            a2 = fmaf(x2.x, w0, a2); a2 = fmaf(x2.y, w1, a2); a2 = fmaf(x2.z, w2, a2); a2 = fmaf(x2.w, w3, a2);
            a3 = fmaf(x3.x, w0, a3); a3 = fmaf(x3.y, w1, a3); a3 = fmaf(x3.z, w2, a3); a3 = fmaf(x3.w, w3, a3);
        }
        hA[0][t] = fmaxf(a0, 0.f); hA[1][t] = fmaxf(a1, 0.f);
        hA[2][t] = fmaxf(a2, 0.f); hA[3][t] = fmaxf(a3, 0.f);
    }
    __syncthreads();
    // L2: hA @ aw2 -> hB
    {
        float bz = ab2[t];
        float a0 = bz, a1 = bz, a2 = bz, a3 = bz;
        for (int k = 0; k < 512; k += 4) {
            float w0 = aw2[(k + 0) * 512 + t];
            float w1 = aw2[(k + 1) * 512 + t];
            float w2 = aw2[(k + 2) * 512 + t];
            float w3 = aw2[(k + 3) * 512 + t];
            float4 x0 = *(const float4*)&hA[0][k];
            float4 x1 = *(const float4*)&hA[1][k];
            float4 x2 = *(const float4*)&hA[2][k];
            float4 x3 = *(const float4*)&hA[3][k];
            a0 = fmaf(x0.x, w0, a0); a0 = fmaf(x0.y, w1, a0); a0 = fmaf(x0.z, w2, a0); a0 = fmaf(x0.w, w3, a0);
            a1 = fmaf(x1.x, w0, a1); a1 = fmaf(x1.y, w1, a1); a1 = fmaf(x1.z, w2, a1); a1 = fmaf(x1.w, w3, a1);
            a2 = fmaf(x2.x, w0, a2); a2 = fmaf(x2.y, w1, a2); a2 = fmaf(x2.z, w2, a2); a2 = fmaf(x2.w, w3, a2);
            a3 = fmaf(x3.x, w0, a3); a3 = fmaf(x3.y, w1, a3); a3 = fmaf(x3.z, w2, a3); a3 = fmaf(x3.w, w3, a3);
        }
        hB[0][t] = fmaxf(a0, 0.f); hB[1][t] = fmaxf(a1, 0.f);
        hB[2][t] = fmaxf(a2, 0.f); hB[3][t] = fmaxf(a3, 0.f);
    }
    __syncthreads();
    // L3: hB @ aw3 -> hA
    {
        float bz = ab3[t];
        float a0 = bz, a1 = bz, a2 = bz, a3 = bz;
        for (int k = 0; k < 512; k += 4) {
            float w0 = aw3[(k + 0) * 512 + t];
            float w1 = aw3[(k + 1) * 512 + t];
            float w2 = aw3[(k + 2) * 512 + t];
            float w3 = aw3[(k + 3) * 512 + t];
            float4 x0 = *(const float4*)&hB[0][k];
            float4 x1 = *(const float4*)&hB[1][k];
            float4 x2 = *(const float4*)&hB[2][k];
            float4 x3 = *(const float4*)&hB[3][k];
            a0 = fmaf(x0.x, w0, a0); a0 = fmaf(x0.y, w1, a0); a0 = fmaf(x0.z, w2, a0); a0 = fmaf(x0.w, w3, a0);
            a1 = fmaf(x1.x, w0, a1); a1 = fmaf(x1.y, w1, a1); a1 = fmaf(x1.z, w2, a1); a1 = fmaf(x1.w, w3, a1);
            a2 = fmaf(x2.x, w0, a2); a2 = fmaf(x2.y, w1, a2); a2 = fmaf(x2.z, w2, a2); a2 = fmaf(x2.w, w3, a2);
            a3 = fmaf(x3.x, w0, a3); a3 = fmaf(x3.y, w1, a3); a3 = fmaf(x3.z, w2, a3); a3 = fmaf(x3.w, w3, a3);
        }
        hA[0][t] = fmaxf(a0, 0.f); hA[1][t] = fmaxf(a1, 0.f);
        hA[2][t] = fmaxf(a2, 0.f); hA[3][t] = fmaxf(a3, 0.f);
    }
    __syncthreads();
    // L4 (64 outs per row) + L2-normalize; wave = one row
    if (t < 256) {
        int r = t >> 6, o = t & 63;
        float acc = ab4[o];
        for (int k = 0; k < 512; k += 4) {
            float4 hv = *(const float4*)&hA[r][k];
            acc = fmaf(hv.x, aw4[(k + 0) * 64 + o], acc);
            acc = fmaf(hv.y, aw4[(k + 1) * 64 + o], acc);
            acc = fmaf(hv.z, aw4[(k + 2) * 64 + o], acc);
            acc = fmaf(hv.w, aw4[(k + 3) * 64 + o], acc);
        }
        float ss = acc * acc;
        #pragma unroll
        for (int off = 32; off > 0; off >>= 1) ss += __shfl_xor(ss, off);
        ang[(b0 + r) * 64 + o] = acc / (sqrtf(ss) + 1e-5f);
    }
}

// ---------------- K2: logits[256][PN] = ang @ ap^T (f32 GEMM, 64x64 tiles) ----------------
__global__ __launch_bounds__(256) void k2_logits(
    const float* __restrict__ ang, const float* __restrict__ ap,
    float* __restrict__ logits)
{
    __shared__ __align__(16) float As[64][68];  // [k][row]
    __shared__ __align__(16) float Bs[64][68];  // [k][col]
    int t = threadIdx.x;
    int cbase = blockIdx.x * 64;
    int rbase = blockIdx.y * 64;
    #pragma unroll
    for (int i = 0; i < 4; ++i) {
        int e = i * 256 + t;
        int r = e >> 4, k4 = e & 15;
        float4 v = *(const float4*)&ang[(rbase + r) * 64 + k4 * 4];
        As[k4 * 4 + 0][r] = v.x; As[k4 * 4 + 1][r] = v.y;
        As[k4 * 4 + 2][r] = v.z; As[k4 * 4 + 3][r] = v.w;
    }
    #pragma unroll
    for (int i = 0; i < 4; ++i) {
        int e = i * 256 + t;
        int c = e >> 4, k4 = e & 15;
        int gc = cbase + c;
        float4 v = make_float4(0.f, 0.f, 0.f, 0.f);
        if (gc < PN) v = *(const float4*)&ap[(size_t)gc * 64 + k4 * 4];
        Bs[k4 * 4 + 0][c] = v.x; Bs[k4 * 4 + 1][c] = v.y;
        Bs[k4 * 4 + 2][c] = v.z; Bs[k4 * 4 + 3][c] = v.w;
    }
    __syncthreads();
    int tx = t & 15, ty = t >> 4;
    float acc[4][4];
    #pragma unroll
    for (int i = 0; i < 4; ++i)
        #pragma unroll
        for (int j = 0; j < 4; ++j) acc[i][j] = 0.f;
    #pragma unroll 8
    for (int k = 0; k < 64; ++k) {
        float4 av = *(const float4*)&As[k][ty * 4];
        float4 bv = *(const float4*)&Bs[k][tx * 4];
        acc[0][0] = fmaf(av.x, bv.x, acc[0][0]); acc[0][1] = fmaf(av.x, bv.y, acc[0][1]);
        acc[0][2] = fmaf(av.x, bv.z, acc[0][2]); acc[0][3] = fmaf(av.x, bv.w, acc[0][3]);
        acc[1][0] = fmaf(av.y, bv.x, acc[1][0]); acc[1][1] = fmaf(av.y, bv.y, acc[1][1]);
        acc[1][2] = fmaf(av.y, bv.z, acc[1][2]); acc[1][3] = fmaf(av.y, bv.w, acc[1][3]);
        acc[2][0] = fmaf(av.z, bv.x, acc[2][0]); acc[2][1] = fmaf(av.z, bv.y, acc[2][1]);
        acc[2][2] = fmaf(av.z, bv.z, acc[2][2]); acc[2][3] = fmaf(av.z, bv.w, acc[2][3]);
        acc[3][0] = fmaf(av.w, bv.x, acc[3][0]); acc[3][1] = fmaf(av.w, bv.y, acc[3][1]);
        acc[3][2] = fmaf(av.w, bv.z, acc[3][2]); acc[3][3] = fmaf(av.w, bv.w, acc[3][3]);
    }
    int gc = cbase + tx * 4;
    if (gc < PN) {
        #pragma unroll
        for (int i = 0; i < 4; ++i) {
            int rr = rbase + ty * 4 + i;
            *(float4*)&logits[(size_t)rr * PN + gc] =
                make_float4(acc[i][0], acc[i][1], acc[i][2], acc[i][3]);
        }
    }
}

// ---------------- K3: per-row softmax-sum + exact top-128 ----------------
#define CAP 2048
__global__ __launch_bounds__(1024) void k3_topk(
    const float* __restrict__ logits, const int* __restrict__ nin,
    float* __restrict__ srted, int* __restrict__ sidx,
    float* __restrict__ maskp, float* __restrict__ nrp)
{
    __shared__ unsigned int hist[8192];
    __shared__ unsigned int chunks[256];
    __shared__ float wsum[16];
    __shared__ float s_inv;
    __shared__ int s_T;
    __shared__ unsigned int ccnt;
    __shared__ unsigned int ckey[CAP];
    __shared__ unsigned int cidx[CAP];
    __shared__ unsigned long long arr[CAP];

    int r = blockIdx.x;
    int t = threadIdx.x;
    const float4* row4 = (const float4*)(logits + (size_t)r * PN);
    for (int i = t; i < 8192; i += 1024) hist[i] = 0u;
    if (t == 0) ccnt = 0u;
    __syncthreads();

    float es = 0.f;
    for (int i = t; i < PN / 4; i += 1024) {
        float4 v = row4[i];
        es += expf(v.x) + expf(v.y) + expf(v.z) + expf(v.w);
        atomicAdd(&hist[sortkey(v.x) >> 19], 1u);
        atomicAdd(&hist[sortkey(v.y) >> 19], 1u);
        atomicAdd(&hist[sortkey(v.z) >> 19], 1u);
        atomicAdd(&hist[sortkey(v.w) >> 19], 1u);
    }
    #pragma unroll
    for (int off = 32; off > 0; off >>= 1) es += __shfl_xor(es, off);
    if ((t & 63) == 0) wsum[t >> 6] = es;
    __syncthreads();
    if (t == 0) {
        float s = 0.f;
        for (int i = 0; i < 16; ++i) s += wsum[i];
        s_inv = 1.0f / s;
    }
    if (t < 256) {
        unsigned int cs = 0u;
        for (int b = 0; b < 32; ++b) cs += hist[t * 32 + b];
        chunks[t] = cs;
    }
    __syncthreads();
    if (t == 0) {
        unsigned int cum = 0u; int T = 0;
        for (int ci = 255; ci >= 0; --ci) {
            if (cum + chunks[ci] >= 128u) {
                for (int bb = ci * 32 + 31; ; --bb) {
                    unsigned int h = hist[bb];
                    if (cum + h >= 128u) { T = bb; break; }
                    cum += h;
                }
                break;
            }
            cum += chunks[ci];
        }
        s_T = T;
    }
    __syncthreads();
    int T = s_T;
    for (int i = t; i < PN / 4; i += 1024) {
        float4 v = row4[i];
        unsigned int kk;
        kk = sortkey(v.x);
        if ((int)(kk >> 19) >= T) { unsigned int p = atomicAdd(&ccnt, 1u); if (p < CAP) { ckey[p] = kk; cidx[p] = 4 * i + 0; } }
        kk = sortkey(v.y);
        if ((int)(kk >> 19) >= T) { unsigned int p = atomicAdd(&ccnt, 1u); if (p < CAP) { ckey[p] = kk; cidx[p] = 4 * i + 1; } }
        kk = sortkey(v.z);
        if ((int)(kk >> 19) >= T) { unsigned int p = atomicAdd(&ccnt, 1u); if (p < CAP) { ckey[p] = kk; cidx[p] = 4 * i + 2; } }
        kk = sortkey(v.w);
        if ((int)(kk >> 19) >= T) { unsigned int p = atomicAdd(&ccnt, 1u); if (p < CAP) { ckey[p] = kk; cidx[p] = 4 * i + 3; } }
    }
    __syncthreads();
    int nc = (int)min(ccnt, (unsigned int)CAP);
    int P = 128;
    while (P < nc) P <<= 1;
    for (int i = t; i < P; i += 1024)
        arr[i] = (i < nc) ? ((((unsigned long long)ckey[i]) << 32) | (unsigned int)(~cidx[i])) : 0ull;
    __syncthreads();
    for (int kk = 2; kk <= P; kk <<= 1) {
        for (int j = kk >> 1; j > 0; j >>= 1) {
            for (int i = t; i < P; i += 1024) {
                int l = i ^ j;
                if (l > i) {
                    unsigned long long a = arr[i], b = arr[l];
                    bool up = ((i & kk) == 0);
                    if (up ? (a < b) : (a > b)) { arr[i] = b; arr[l] = a; }
                }
            }
            __syncthreads();
        }
    }
    int nr = nin[r]; nr = nr < 1 ? 1 : (nr > 128 ? 128 : nr);
    if (t < 128) {
        unsigned long long c = arr[t];
        unsigned int key = (unsigned int)(c >> 32);
        unsigned int idx = ~((unsigned int)c);
        unsigned int u = (key & 0x80000000u) ? (key ^ 0x80000000u) : ~key;
        float v = __uint_as_float(u);
        srted[r * 128 + t] = expf(v) * s_inv;
        sidx[r * 128 + t] = (int)idx;
        maskp[r * 128 + t] = (t < nr) ? 1.0f : 0.0f;
    }
    if (t == 0) nrp[r] = (float)nr;
}

// ---------------- K4: gather + modulate + 3-layer MLP -> out ----------------
__global__ __launch_bounds__(256) void k4_outmlp(
    const float* __restrict__ points, const float* __restrict__ latent,
    const float* __restrict__ srted, const int* __restrict__ sidx,
    const float* __restrict__ l1w, const float* __restrict__ l1b,
    const float* __restrict__ l2w, const float* __restrict__ l2b,
    const float* __restrict__ ow1, const float* __restrict__ ob1,
    const float* __restrict__ ow2, const float* __restrict__ ob2,
    const float* __restrict__ ow3, const float* __restrict__ ob3,
    float* __restrict__ outp)
{
    __shared__ __align__(16) float Xs[16][512];
    __shared__ __align__(16) float Hs[16][512];
    __shared__ float s_s[16];
    __shared__ int s_pi[16];
    __shared__ int s_b[16];
    int t = threadIdx.x;
    int tok0 = blockIdx.x * 16;
    if (t < 16) {
        int token = tok0 + t;
        int b = token >> 7, kk = token & 127;
        s_s[t] = 128.0f * srted[b * 128 + kk];
        s_pi[t] = sidx[b * 128 + kk];
        s_b[t] = b;
    }
    __syncthreads();
    {
        float w1 = l1w[t], b1 = l1b[t], w2 = l2w[t], b2 = l2b[t];
        for (int tt = 0; tt < 16; ++tt) {
            float s = s_s[tt];
            float p = points[(size_t)s_pi[tt] * 256 + t];
            float alpha = fmaf(s, w1, b1);
            float beta = fmaf(s, w2, b2);
            Xs[tt][t] = fmaf(alpha, p, beta);
            Xs[tt][256 + t] = latent[s_b[tt] * 256 + t];
        }
    }
    __syncthreads();
    // layer 1: Xs[16][512] @ ow1[512][512] -> Hs (relu). 8 outs x 4 toks / thread.
    {
        int o0 = t & 63, grp = t >> 6;
        float acc[8][4];
        #pragma unroll
        for (int oi = 0; oi < 8; ++oi) {
            float bz = ob1[o0 + 64 * oi];
            #pragma unroll
            for (int tj = 0; tj < 4; ++tj) acc[oi][tj] = bz;
        }
        for (int k = 0; k < 512; k += 4) {
            float w[4][8];
            #pragma unroll
            for (int ki = 0; ki < 4; ++ki)
                #pragma unroll
                for (int oi = 0; oi < 8; ++oi)
                    w[ki][oi] = ow1[(k + ki) * 512 + o0 + 64 * oi];
            #pragma unroll
            for (int tj = 0; tj < 4; ++tj) {
                float4 xv = *(const float4*)&Xs[grp * 4 + tj][k];
                #pragma unroll
                for (int oi = 0; oi < 8; ++oi) {
                    acc[oi][tj] = fmaf(xv.x, w[0][oi], acc[oi][tj]);
                    acc[oi][tj] = fmaf(xv.y, w[1][oi], acc[oi][tj]);
                    acc[oi][tj] = fmaf(xv.z, w[2][oi], acc[oi][tj]);
                    acc[oi][tj] = fmaf(xv.w, w[3][oi], acc[oi][tj]);
                }
            }
        }
        #pragma unroll
        for (int oi = 0; oi < 8; ++oi)
            #pragma unroll
            for (int tj = 0; tj < 4; ++tj)
                Hs[grp * 4 + tj][o0 + 64 * oi] = fmaxf(acc[oi][tj], 0.f);
    }
    __syncthreads();
    // layer 2: Hs[16][512] @ ow2[512][256] -> Xs[..][0..255] (relu). 4 outs x 4 toks.
    {
        int o0 = t & 63, grp = t >> 6;
        float acc[4][4];
        #pragma unroll
        for (int oi = 0; oi < 4; ++oi) {
            float bz = ob2[o0 + 64 * oi];
            #pragma unroll
            for (int tj = 0; tj < 4; ++tj) acc[oi][tj] = bz;
        }
        for (int k = 0; k < 512; k += 4) {
            float w[4][4];
            #pragma unroll
            for (int ki = 0; ki < 4; ++ki)
                #pragma unroll
                for (int oi = 0; oi < 4; ++oi)
                    w[ki][oi] = ow2[(k + ki) * 256 + o0 + 64 * oi];
            #pragma unroll
            for (int tj = 0; tj < 4; ++tj) {
                float4 xv = *(const float4*)&Hs[grp * 4 + tj][k];
                #pragma unroll
                for (int oi = 0; oi < 4; ++oi) {
                    acc[oi][tj] = fmaf(xv.x, w[0][oi], acc[oi][tj]);
                    acc[oi][tj] = fmaf(xv.y, w[1][oi], acc[oi][tj]);
                    acc[oi][tj] = fmaf(xv.z, w[2][oi], acc[oi][tj]);
                    acc[oi][tj] = fmaf(xv.w, w[3][oi], acc[oi][tj]);
                }
            }
        }
        #pragma unroll
        for (int oi = 0; oi < 4; ++oi)
            #pragma unroll
            for (int tj = 0; tj < 4; ++tj)
                Xs[grp * 4 + tj][o0 + 64 * oi] = fmaxf(acc[oi][tj], 0.f);
    }
    __syncthreads();
    // layer 3: Xs[16][0..255] @ ow3[256][256] -> out. 4 outs x 4 toks.
    {
        int o0 = t & 63, grp = t >> 6;
        float acc[4][4];
        #pragma unroll
        for (int oi = 0; oi < 4; ++oi) {
            float bz = ob3[o0 + 64 * oi];
            #pragma unroll
            for (int tj = 0; tj < 4; ++tj) acc[oi][tj] = bz;
        }
        for (int k = 0; k < 256; k += 4) {
            float w[4][4];
            #pragma unroll
            for (int ki = 0; ki < 4; ++ki)
                #pragma unroll
                for (int oi = 0; oi < 4; ++oi)
                    w[ki][oi] = ow3[(k + ki) * 256 + o0 + 64 * oi];
            #pragma unroll
            for (int tj = 0; tj < 4; ++tj) {
                float4 xv = *(const float4*)&Xs[grp * 4 + tj][k];
                #pragma unroll
                for (int oi = 0; oi < 4; ++oi) {
                    acc[oi][tj] = fmaf(xv.x, w[0][oi], acc[oi][tj]);
                    acc[oi][tj] = fmaf(xv.y, w[1][oi], acc[oi][tj]);
                    acc[oi][tj] = fmaf(xv.z, w[2][oi], acc[oi][tj]);
                    acc[oi][tj] = fmaf(xv.w, w[3][oi], acc[oi][tj]);
                }
            }
        }
        #pragma unroll
        for (int tj = 0; tj < 4; ++tj) {
            int tt = grp * 4 + tj;
            #pragma unroll
            for (int oi = 0; oi < 4; ++oi)
                outp[(size_t)(tok0 + tt) * 256 + o0 + 64 * oi] = acc[oi][tj];
        }
    }
}

extern "C" void kernel_launch(void* const* d_in, const int* in_sizes, int n_in,
                              void* d_out, int out_size, void* d_ws, size_t ws_size,
                              hipStream_t stream) {
    (void)in_sizes; (void)n_in; (void)out_size; (void)ws_size;
    const float* latent = (const float*)d_in[0];
    const int*   nin    = (const int*)d_in[1];
    const float* points = (const float*)d_in[2];
    const float* ap     = (const float*)d_in[3];
    const float* aw1 = (const float*)d_in[4];  const float* ab1 = (const float*)d_in[5];
    const float* aw2 = (const float*)d_in[6];  const float* ab2 = (const float*)d_in[7];
    const float* aw3 = (const float*)d_in[8];  const float* ab3 = (const float*)d_in[9];
    const float* aw4 = (const float*)d_in[10]; const float* ab4 = (const float*)d_in[11];
    const float* l1w = (const float*)d_in[12]; const float* l1b = (const float*)d_in[13];
    const float* l2w = (const float*)d_in[14]; const float* l2b = (const float*)d_in[15];
    const float* ow1 = (const float*)d_in[16]; const float* ob1 = (const float*)d_in[17];
    const float* ow2 = (const float*)d_in[18]; const float* ob2 = (const float*)d_in[19];
    const float* ow3 = (const float*)d_in[20]; const float* ob3 = (const float*)d_in[21];

    float* ws    = (float*)d_ws;
    float* ang   = ws;                      // 256*64
    float* srted = ws + 16384;              // 256*128
    int*   sidx  = (int*)(ws + 49152);      // 256*128
    float* logit = ws + 81920;              // 256*100000

    float* outp  = (float*)d_out;           // [32768][256]
    float* maskp = outp + 8388608;          // [256][128]
    float* nrp   = outp + 8421376;          // [256]

    hipLaunchKernelGGL(k1_angle_mlp, dim3(64), dim3(512), 0, stream,
                       latent, aw1, ab1, aw2, ab2, aw3, ab3, aw4, ab4, ang);
    hipLaunchKernelGGL(k2_logits, dim3((PN + 63) / 64, 4), dim3(256), 0, stream,
                       ang, ap, logit);
    hipLaunchKernelGGL(k3_topk, dim3(256), dim3(1024), 0, stream,
                       logit, nin, srted, sidx, maskp, nrp);
    hipLaunchKernelGGL(k4_outmlp, dim3(2048), dim3(256), 0, stream,
                       points, latent, srted, sidx, l1w, l1b, l2w, l2b,
                       ow1, ob1, ow2, ob2, ow3, ob3, outp);
}

// Round 2
// 292.398 us; speedup vs baseline: 2.4830x; 2.4830x over previous
//
#include <hip/hip_runtime.h>

#define PN 100000

typedef _Float16 f16;
typedef _Float16 f16x8 __attribute__((ext_vector_type(8)));
typedef float f32x4 __attribute__((ext_vector_type(4)));

__device__ __forceinline__ unsigned int sortkey(float f) {
    unsigned int u = __float_as_uint(f);
    return u ^ ((u & 0x80000000u) ? 0xFFFFFFFFu : 0x80000000u);
}

__device__ __forceinline__ void gload_lds16(const void* g, void* l) {
    __builtin_amdgcn_global_load_lds((const __attribute__((address_space(1))) void*)g,
                                     (__attribute__((address_space(3))) void*)l, 16, 0, 0);
}

// ---------------- K1: angle MLP + row normalize -> ang [256][64] ----------------
__global__ __launch_bounds__(512) void k1_angle_mlp(
    const float* __restrict__ latent,
    const float* __restrict__ aw1, const float* __restrict__ ab1,
    const float* __restrict__ aw2, const float* __restrict__ ab2,
    const float* __restrict__ aw3, const float* __restrict__ ab3,
    const float* __restrict__ aw4, const float* __restrict__ ab4,
    float* __restrict__ ang)
{
    __shared__ __align__(16) float xs[4][256];
    __shared__ __align__(16) float hA[4][512];
    __shared__ __align__(16) float hB[4][512];
    int t = threadIdx.x;
    int b0 = blockIdx.x * 4;
    for (int i = t; i < 4 * 256; i += 512) xs[i >> 8][i & 255] = latent[b0 * 256 + i];
    __syncthreads();
    {
        float bz = ab1[t];
        float a0 = bz, a1 = bz, a2 = bz, a3 = bz;
        for (int k = 0; k < 256; k += 4) {
            float w0 = aw1[(k + 0) * 512 + t];
            float w1 = aw1[(k + 1) * 512 + t];
            float w2 = aw1[(k + 2) * 512 + t];
            float w3 = aw1[(k + 3) * 512 + t];
            float4 x0 = *(const float4*)&xs[0][k];
            float4 x1 = *(const float4*)&xs[1][k];
            float4 x2 = *(const float4*)&xs[2][k];
            float4 x3 = *(const float4*)&xs[3][k];
            a0 = fmaf(x0.x, w0, a0); a0 = fmaf(x0.y, w1, a0); a0 = fmaf(x0.z, w2, a0); a0 = fmaf(x0.w, w3, a0);
            a1 = fmaf(x1.x, w0, a1); a1 = fmaf(x1.y, w1, a1); a1 = fmaf(x1.z, w2, a1); a1 = fmaf(x1.w, w3, a1);
            a2 = fmaf(x2.x, w0, a2); a2 = fmaf(x2.y, w1, a2); a2 = fmaf(x2.z, w2, a2); a2 = fmaf(x2.w, w3, a2);
            a3 = fmaf(x3.x, w0, a3); a3 = fmaf(x3.y, w1, a3); a3 = fmaf(x3.z, w2, a3); a3 = fmaf(x3.w, w3, a3);
        }
        hA[0][t] = fmaxf(a0, 0.f); hA[1][t] = fmaxf(a1, 0.f);
        hA[2][t] = fmaxf(a2, 0.f); hA[3][t] = fmaxf(a3, 0.f);
    }
    __syncthreads();
    {
        float bz = ab2[t];
        float a0 = bz, a1 = bz, a2 = bz, a3 = bz;
        for (int k = 0; k < 512; k += 4) {
            float w0 = aw2[(k + 0) * 512 + t];
            float w1 = aw2[(k + 1) * 512 + t];
            float w2 = aw2[(k + 2) * 512 + t];
            float w3 = aw2[(k + 3) * 512 + t];
            float4 x0 = *(const float4*)&hA[0][k];
            float4 x1 = *(const float4*)&hA[1][k];
            float4 x2 = *(const float4*)&hA[2][k];
            float4 x3 = *(const float4*)&hA[3][k];
            a0 = fmaf(x0.x, w0, a0); a0 = fmaf(x0.y, w1, a0); a0 = fmaf(x0.z, w2, a0); a0 = fmaf(x0.w, w3, a0);
            a1 = fmaf(x1.x, w0, a1); a1 = fmaf(x1.y, w1, a1); a1 = fmaf(x1.z, w2, a1); a1 = fmaf(x1.w, w3, a1);
            a2 = fmaf(x2.x, w0, a2); a2 = fmaf(x2.y, w1, a2); a2 = fmaf(x2.z, w2, a2); a2 = fmaf(x2.w, w3, a2);
            a3 = fmaf(x3.x, w0, a3); a3 = fmaf(x3.y, w1, a3); a3 = fmaf(x3.z, w2, a3); a3 = fmaf(x3.w, w3, a3);
        }
        hB[0][t] = fmaxf(a0, 0.f); hB[1][t] = fmaxf(a1, 0.f);
        hB[2][t] = fmaxf(a2, 0.f); hB[3][t] = fmaxf(a3, 0.f);
    }
    __syncthreads();
    {
        float bz = ab3[t];
        float a0 = bz, a1 = bz, a2 = bz, a3 = bz;
        for (int k = 0; k < 512; k += 4) {
            float w0 = aw3[(k + 0) * 512 + t];
            float w1 = aw3[(k + 1) * 512 + t];
            float w2 = aw3[(k + 2) * 512 + t];
            float w3 = aw3[(k + 3) * 512 + t];
            float4 x0 = *(const float4*)&hB[0][k];
            float4 x1 = *(const float4*)&hB[1][k];
            float4 x2 = *(const float4*)&hB[2][k];
            float4 x3 = *(const float4*)&hB[3][k];
            a0 = fmaf(x0.x, w0, a0); a0 = fmaf(x0.y, w1, a0); a0 = fmaf(x0.z, w2, a0); a0 = fmaf(x0.w, w3, a0);
            a1 = fmaf(x1.x, w0, a1); a1 = fmaf(x1.y, w1, a1); a1 = fmaf(x1.z, w2, a1); a1 = fmaf(x1.w, w3, a1);
            a2 = fmaf(x2.x, w0, a2); a2 = fmaf(x2.y, w1, a2); a2 = fmaf(x2.z, w2, a2); a2 = fmaf(x2.w, w3, a2);
            a3 = fmaf(x3.x, w0, a3); a3 = fmaf(x3.y, w1, a3); a3 = fmaf(x3.z, w2, a3); a3 = fmaf(x3.w, w3, a3);
        }
        hA[0][t] = fmaxf(a0, 0.f); hA[1][t] = fmaxf(a1, 0.f);
        hA[2][t] = fmaxf(a2, 0.f); hA[3][t] = fmaxf(a3, 0.f);
    }
    __syncthreads();
    if (t < 256) {
        int r = t >> 6, o = t & 63;
        float acc = ab4[o];
        for (int k = 0; k < 512; k += 4) {
            float4 hv = *(const float4*)&hA[r][k];
            acc = fmaf(hv.x, aw4[(k + 0) * 64 + o], acc);
            acc = fmaf(hv.y, aw4[(k + 1) * 64 + o], acc);
            acc = fmaf(hv.z, aw4[(k + 2) * 64 + o], acc);
            acc = fmaf(hv.w, aw4[(k + 3) * 64 + o], acc);
        }
        float ss = acc * acc;
        #pragma unroll
        for (int off = 32; off > 0; off >>= 1) ss += __shfl_xor(ss, off);
        ang[(b0 + r) * 64 + o] = acc / (sqrtf(ss) + 1e-5f);
    }
}

// ---------------- K2: logits[256][PN] = ang @ ap^T (f32 GEMM) ----------------
__global__ __launch_bounds__(256) void k2_logits(
    const float* __restrict__ ang, const float* __restrict__ ap,
    float* __restrict__ logits)
{
    __shared__ __align__(16) float As[64][68];
    __shared__ __align__(16) float Bs[64][68];
    int t = threadIdx.x;
    int cbase = blockIdx.x * 64;
    int rbase = blockIdx.y * 64;
    #pragma unroll
    for (int i = 0; i < 4; ++i) {
        int e = i * 256 + t;
        int r = e >> 4, k4 = e & 15;
        float4 v = *(const float4*)&ang[(rbase + r) * 64 + k4 * 4];
        As[k4 * 4 + 0][r] = v.x; As[k4 * 4 + 1][r] = v.y;
        As[k4 * 4 + 2][r] = v.z; As[k4 * 4 + 3][r] = v.w;
    }
    #pragma unroll
    for (int i = 0; i < 4; ++i) {
        int e = i * 256 + t;
        int c = e >> 4, k4 = e & 15;
        int gc = cbase + c;
        float4 v = make_float4(0.f, 0.f, 0.f, 0.f);
        if (gc < PN) v = *(const float4*)&ap[(size_t)gc * 64 + k4 * 4];
        Bs[k4 * 4 + 0][c] = v.x; Bs[k4 * 4 + 1][c] = v.y;
        Bs[k4 * 4 + 2][c] = v.z; Bs[k4 * 4 + 3][c] = v.w;
    }
    __syncthreads();
    int tx = t & 15, ty = t >> 4;
    float acc[4][4];
    #pragma unroll
    for (int i = 0; i < 4; ++i)
        #pragma unroll
        for (int j = 0; j < 4; ++j) acc[i][j] = 0.f;
    #pragma unroll 8
    for (int k = 0; k < 64; ++k) {
        float4 av = *(const float4*)&As[k][ty * 4];
        float4 bv = *(const float4*)&Bs[k][tx * 4];
        acc[0][0] = fmaf(av.x, bv.x, acc[0][0]); acc[0][1] = fmaf(av.x, bv.y, acc[0][1]);
        acc[0][2] = fmaf(av.x, bv.z, acc[0][2]); acc[0][3] = fmaf(av.x, bv.w, acc[0][3]);
        acc[1][0] = fmaf(av.y, bv.x, acc[1][0]); acc[1][1] = fmaf(av.y, bv.y, acc[1][1]);
        acc[1][2] = fmaf(av.y, bv.z, acc[1][2]); acc[1][3] = fmaf(av.y, bv.w, acc[1][3]);
        acc[2][0] = fmaf(av.z, bv.x, acc[2][0]); acc[2][1] = fmaf(av.z, bv.y, acc[2][1]);
        acc[2][2] = fmaf(av.z, bv.z, acc[2][2]); acc[2][3] = fmaf(av.z, bv.w, acc[2][3]);
        acc[3][0] = fmaf(av.w, bv.x, acc[3][0]); acc[3][1] = fmaf(av.w, bv.y, acc[3][1]);
        acc[3][2] = fmaf(av.w, bv.z, acc[3][2]); acc[3][3] = fmaf(av.w, bv.w, acc[3][3]);
    }
    int gc = cbase + tx * 4;
    if (gc < PN) {
        #pragma unroll
        for (int i = 0; i < 4; ++i) {
            int rr = rbase + ty * 4 + i;
            *(float4*)&logits[(size_t)rr * PN + gc] =
                make_float4(acc[i][0], acc[i][1], acc[i][2], acc[i][3]);
        }
    }
}

// ---------------- K3: per-row softmax-sum + exact top-128 ----------------
#define CAP 2048
__global__ __launch_bounds__(1024) void k3_topk(
    const float* __restrict__ logits, const int* __restrict__ nin,
    float* __restrict__ srted, int* __restrict__ sidx,
    float* __restrict__ maskp, float* __restrict__ nrp)
{
    __shared__ unsigned int hist[8192];
    __shared__ unsigned int chunks[256];
    __shared__ float wsum[16];
    __shared__ float s_inv;
    __shared__ int s_T;
    __shared__ unsigned int ccnt;
    __shared__ unsigned int ckey[CAP];
    __shared__ unsigned int cidx[CAP];
    __shared__ unsigned long long arr[CAP];

    int r = blockIdx.x;
    int t = threadIdx.x;
    const float4* row4 = (const float4*)(logits + (size_t)r * PN);
    for (int i = t; i < 8192; i += 1024) hist[i] = 0u;
    if (t == 0) ccnt = 0u;
    __syncthreads();

    float es = 0.f;
    for (int i = t; i < PN / 4; i += 1024) {
        float4 v = row4[i];
        es += expf(v.x) + expf(v.y) + expf(v.z) + expf(v.w);
        atomicAdd(&hist[sortkey(v.x) >> 19], 1u);
        atomicAdd(&hist[sortkey(v.y) >> 19], 1u);
        atomicAdd(&hist[sortkey(v.z) >> 19], 1u);
        atomicAdd(&hist[sortkey(v.w) >> 19], 1u);
    }
    #pragma unroll
    for (int off = 32; off > 0; off >>= 1) es += __shfl_xor(es, off);
    if ((t & 63) == 0) wsum[t >> 6] = es;
    __syncthreads();
    if (t == 0) {
        float s = 0.f;
        for (int i = 0; i < 16; ++i) s += wsum[i];
        s_inv = 1.0f / s;
    }
    if (t < 256) {
        unsigned int cs = 0u;
        for (int b = 0; b < 32; ++b) cs += hist[t * 32 + b];
        chunks[t] = cs;
    }
    __syncthreads();
    if (t == 0) {
        unsigned int cum = 0u; int T = 0;
        for (int ci = 255; ci >= 0; --ci) {
            if (cum + chunks[ci] >= 128u) {
                for (int bb = ci * 32 + 31; ; --bb) {
                    unsigned int h = hist[bb];
                    if (cum + h >= 128u) { T = bb; break; }
                    cum += h;
                }
                break;
            }
            cum += chunks[ci];
        }
        s_T = T;
    }
    __syncthreads();
    int T = s_T;
    for (int i = t; i < PN / 4; i += 1024) {
        float4 v = row4[i];
        unsigned int kk;
        kk = sortkey(v.x);
        if ((int)(kk >> 19) >= T) { unsigned int p = atomicAdd(&ccnt, 1u); if (p < CAP) { ckey[p] = kk; cidx[p] = 4 * i + 0; } }
        kk = sortkey(v.y);
        if ((int)(kk >> 19) >= T) { unsigned int p = atomicAdd(&ccnt, 1u); if (p < CAP) { ckey[p] = kk; cidx[p] = 4 * i + 1; } }
        kk = sortkey(v.z);
        if ((int)(kk >> 19) >= T) { unsigned int p = atomicAdd(&ccnt, 1u); if (p < CAP) { ckey[p] = kk; cidx[p] = 4 * i + 2; } }
        kk = sortkey(v.w);
        if ((int)(kk >> 19) >= T) { unsigned int p = atomicAdd(&ccnt, 1u); if (p < CAP) { ckey[p] = kk; cidx[p] = 4 * i + 3; } }
    }
    __syncthreads();
    int nc = (int)min(ccnt, (unsigned int)CAP);
    int P = 128;
    while (P < nc) P <<= 1;
    for (int i = t; i < P; i += 1024)
        arr[i] = (i < nc) ? ((((unsigned long long)ckey[i]) << 32) | (unsigned int)(~cidx[i])) : 0ull;
    __syncthreads();
    for (int kk = 2; kk <= P; kk <<= 1) {
        for (int j = kk >> 1; j > 0; j >>= 1) {
            for (int i = t; i < P; i += 1024) {
                int l = i ^ j;
                if (l > i) {
                    unsigned long long a = arr[i], b = arr[l];
                    bool up = ((i & kk) == 0);
                    if (up ? (a < b) : (a > b)) { arr[i] = b; arr[l] = a; }
                }
            }
            __syncthreads();
        }
    }
    int nr = nin[r]; nr = nr < 1 ? 1 : (nr > 128 ? 128 : nr);
    if (t < 128) {
        unsigned long long c = arr[t];
        unsigned int key = (unsigned int)(c >> 32);
        unsigned int idx = ~((unsigned int)c);
        unsigned int u = (key & 0x80000000u) ? (key ^ 0x80000000u) : ~key;
        float v = __uint_as_float(u);
        srted[r * 128 + t] = expf(v) * s_inv;
        sidx[r * 128 + t] = (int)idx;
        maskp[r * 128 + t] = (t < nr) ? 1.0f : 0.0f;
    }
    if (t == 0) nrp[r] = (float)nr;
}

// ---------------- W transpose+convert: Wt[n][k] = (f16)W[k][n] ----------------
__global__ __launch_bounds__(256) void k_wconv(
    const float* __restrict__ W, f16* __restrict__ Wt, int K, int N)
{
    int idx = blockIdx.x * 256 + threadIdx.x;
    int n = idx / K, k = idx % K;
    Wt[idx] = (f16)W[(size_t)k * N + n];
}

// ---------------- Build X1[32768][512] f16 = [alpha*sel+beta | latent] ----------------
__global__ __launch_bounds__(256) void k_buildx(
    const float* __restrict__ points, const float* __restrict__ latent,
    const float* __restrict__ srted, const int* __restrict__ sidx,
    const float* __restrict__ l1w, const float* __restrict__ l1b,
    const float* __restrict__ l2w, const float* __restrict__ l2b,
    f16* __restrict__ X1)
{
    __shared__ float s_s[16];
    __shared__ int s_pi[16];
    int t = threadIdx.x;
    int tok0 = blockIdx.x * 16;
    if (t < 16) {
        int token = tok0 + t;
        s_s[t] = 128.0f * srted[token];
        s_pi[t] = sidx[token];
    }
    __syncthreads();
    float w1 = l1w[t], b1 = l1b[t], w2 = l2w[t], b2 = l2b[t];
    for (int tt = 0; tt < 16; ++tt) {
        int token = tok0 + tt;
        int b = token >> 7;
        float s = s_s[tt];
        float p = points[(size_t)s_pi[tt] * 256 + t];
        float alpha = fmaf(s, w1, b1);
        float beta = fmaf(s, w2, b2);
        X1[(size_t)token * 512 + t] = (f16)fmaf(alpha, p, beta);
        X1[(size_t)token * 512 + 256 + t] = (f16)latent[b * 256 + t];
    }
}

// ---------------- f16 MFMA GEMM: C[M][N] = A[M][K] @ Bt[N][K]^T + bias ----------------
template<int RELU, int OUT_F16>
__global__ __launch_bounds__(256) void gemm_tn(
    const f16* __restrict__ A, const f16* __restrict__ Bt,
    const float* __restrict__ bias,
    f16* __restrict__ Cf16, float* __restrict__ Cf32,
    int N, int K)
{
    __shared__ __align__(16) f16 As[128 * 64];
    __shared__ __align__(16) f16 Bs[128 * 64];
    int tid = threadIdx.x;
    int lane = tid & 63, wave = tid >> 6;
    int brow = blockIdx.y * 128;
    int bcol = blockIdx.x * 128;
    int wr = wave >> 1, wc = wave & 1;

    f32x4 acc[4][4] = {};

    int b_off = tid * 16;        // this thread's 16B within a 4KB chunk
    int sr = b_off >> 7;         // tile row for chunk 0 (rows 0..31)
    int soff = b_off & 127;      // byte offset within the row's 128B k-slab
    char* ldsA = (char*)As + wave * 1024;
    char* ldsB = (char*)Bs + wave * 1024;

    for (int kt = 0; kt < K; kt += 64) {
        #pragma unroll
        for (int c = 0; c < 4; ++c) {
            int r = sr + c * 32;
            const char* ga = (const char*)A + ((size_t)(brow + r) * K + kt) * 2 + soff;
            gload_lds16(ga, ldsA + c * 4096);
        }
        #pragma unroll
        for (int c = 0; c < 4; ++c) {
            int r = sr + c * 32;
            const char* gb = (const char*)Bt + ((size_t)(bcol + r) * K + kt) * 2 + soff;
            gload_lds16(gb, ldsB + c * 4096);
        }
        __syncthreads();
        #pragma unroll
        for (int ks = 0; ks < 2; ++ks) {
            f16x8 af[4], bf[4];
            int kk = ks * 32 + (lane >> 4) * 8;
            #pragma unroll
            for (int i = 0; i < 4; ++i) {
                int row = wr * 64 + i * 16 + (lane & 15);
                af[i] = *(const f16x8*)&As[row * 64 + kk];
                int col = wc * 64 + i * 16 + (lane & 15);
                bf[i] = *(const f16x8*)&Bs[col * 64 + kk];
            }
            #pragma unroll
            for (int i = 0; i < 4; ++i)
                #pragma unroll
                for (int j = 0; j < 4; ++j)
                    acc[i][j] = __builtin_amdgcn_mfma_f32_16x16x32_f16(af[i], bf[j], acc[i][j], 0, 0, 0);
        }
        __syncthreads();
    }

    #pragma unroll
    for (int i = 0; i < 4; ++i) {
        int row = brow + wr * 64 + i * 16 + (lane >> 4) * 4;
        #pragma unroll
        for (int j = 0; j < 4; ++j) {
            int col = bcol + wc * 64 + j * 16 + (lane & 15);
            float bz = bias[col];
            #pragma unroll
            for (int r2 = 0; r2 < 4; ++r2) {
                float v = acc[i][j][r2] + bz;
                if (RELU) v = fmaxf(v, 0.f);
                if (OUT_F16) Cf16[(size_t)(row + r2) * N + col] = (f16)v;
                else         Cf32[(size_t)(row + r2) * N + col] = v;
            }
        }
    }
}

extern "C" void kernel_launch(void* const* d_in, const int* in_sizes, int n_in,
                              void* d_out, int out_size, void* d_ws, size_t ws_size,
                              hipStream_t stream) {
    (void)in_sizes; (void)n_in; (void)out_size; (void)ws_size;
    const float* latent = (const float*)d_in[0];
    const int*   nin    = (const int*)d_in[1];
    const float* points = (const float*)d_in[2];
    const float* ap     = (const float*)d_in[3];
    const float* aw1 = (const float*)d_in[4];  const float* ab1 = (const float*)d_in[5];
    const float* aw2 = (const float*)d_in[6];  const float* ab2 = (const float*)d_in[7];
    const float* aw3 = (const float*)d_in[8];  const float* ab3 = (const float*)d_in[9];
    const float* aw4 = (const float*)d_in[10]; const float* ab4 = (const float*)d_in[11];
    const float* l1w = (const float*)d_in[12]; const float* l1b = (const float*)d_in[13];
    const float* l2w = (const float*)d_in[14]; const float* l2b = (const float*)d_in[15];
    const float* ow1 = (const float*)d_in[16]; const float* ob1 = (const float*)d_in[17];
    const float* ow2 = (const float*)d_in[18]; const float* ob2 = (const float*)d_in[19];
    const float* ow3 = (const float*)d_in[20]; const float* ob3 = (const float*)d_in[21];

    char* wsb = (char*)d_ws;
    float* ang   = (float*)wsb;                 // 64 KB
    float* srted = (float*)(wsb + 65536);       // 128 KB
    int*   sidx  = (int*)(wsb + 196608);        // 128 KB
    float* logit = (float*)(wsb + 327680);      // 102.4 MB

    // dead-logit region reuse (all consumers run after k3):
    char* lz = wsb + 327680;
    f16* X1  = (f16*)lz;                        // 32 MB
    f16* H1  = (f16*)(lz + 33554432);           // 32 MB
    f16* H2  = (f16*)(lz + 67108864);           // 16 MB
    f16* W1t = (f16*)(lz + 83886080);           // 512 KB [512][512]
    f16* W2t = (f16*)(lz + 84410368);           // 256 KB [256][512]
    f16* W3t = (f16*)(lz + 84672512);           // 128 KB [256][256]

    float* outp  = (float*)d_out;               // [32768][256]
    float* maskp = outp + 8388608;              // [256][128]
    float* nrp   = outp + 8421376;              // [256]

    hipLaunchKernelGGL(k1_angle_mlp, dim3(64), dim3(512), 0, stream,
                       latent, aw1, ab1, aw2, ab2, aw3, ab3, aw4, ab4, ang);
    hipLaunchKernelGGL(k2_logits, dim3((PN + 63) / 64, 4), dim3(256), 0, stream,
                       ang, ap, logit);
    hipLaunchKernelGGL(k3_topk, dim3(256), dim3(1024), 0, stream,
                       logit, nin, srted, sidx, maskp, nrp);
    // weight conversions clobber the logit region tail -> must run after k3
    hipLaunchKernelGGL(k_wconv, dim3(512 * 512 / 256), dim3(256), 0, stream, ow1, W1t, 512, 512);
    hipLaunchKernelGGL(k_wconv, dim3(256 * 512 / 256), dim3(256), 0, stream, ow2, W2t, 512, 256);
    hipLaunchKernelGGL(k_wconv, dim3(256 * 256 / 256), dim3(256), 0, stream, ow3, W3t, 256, 256);
    hipLaunchKernelGGL(k_buildx, dim3(2048), dim3(256), 0, stream,
                       points, latent, srted, sidx, l1w, l1b, l2w, l2b, X1);
    hipLaunchKernelGGL((gemm_tn<1, 1>), dim3(4, 256), dim3(256), 0, stream,
                       X1, W1t, ob1, H1, (float*)nullptr, 512, 512);
    hipLaunchKernelGGL((gemm_tn<1, 1>), dim3(2, 256), dim3(256), 0, stream,
                       H1, W2t, ob2, H2, (float*)nullptr, 256, 512);
    hipLaunchKernelGGL((gemm_tn<0, 0>), dim3(2, 256), dim3(256), 0, stream,
                       H2, W3t, ob3, (f16*)nullptr, outp, 256, 256);
}

// Round 3
// 250.217 us; speedup vs baseline: 2.9016x; 1.1686x over previous
//
#include <hip/hip_runtime.h>

#define PN 100000

typedef _Float16 f16;
typedef _Float16 f16x8 __attribute__((ext_vector_type(8)));
typedef float f32x4 __attribute__((ext_vector_type(4)));

__device__ __forceinline__ unsigned int sortkey(float f) {
    unsigned int u = __float_as_uint(f);
    return u ^ ((u & 0x80000000u) ? 0xFFFFFFFFu : 0x80000000u);
}

__device__ __forceinline__ void gload_lds16(const void* g, void* l) {
    __builtin_amdgcn_global_load_lds((const __attribute__((address_space(1))) void*)g,
                                     (__attribute__((address_space(3))) void*)l, 16, 0, 0);
}

// ---------------- k1 layers: Y[256][N] = relu(X[256][K] @ W[K][N] + b) ----------------
// tile: 32 rows x 64 cols, 256 threads, micro 2x4
__global__ __launch_bounds__(256) void k1_layer(
    const float* __restrict__ X, const float* __restrict__ W,
    const float* __restrict__ bias, float* __restrict__ Y,
    int N, int K)
{
    __shared__ __align__(16) float As[64][36];   // [k][row<32]
    __shared__ __align__(16) float Bs[64][68];   // [k][col<64]
    int t = threadIdx.x;
    int cbase = blockIdx.x * 64;
    int rbase = blockIdx.y * 32;
    int tx = t & 15, ty = t >> 4;
    float acc[2][4] = {};

    for (int kt = 0; kt < K; kt += 64) {
        #pragma unroll
        for (int i = 0; i < 2; ++i) {
            int e = i * 256 + t;
            int r = e >> 4, k4 = e & 15;
            float4 v = *(const float4*)&X[(size_t)(rbase + r) * K + kt + k4 * 4];
            As[k4 * 4 + 0][r] = v.x; As[k4 * 4 + 1][r] = v.y;
            As[k4 * 4 + 2][r] = v.z; As[k4 * 4 + 3][r] = v.w;
        }
        #pragma unroll
        for (int i = 0; i < 4; ++i) {
            int e = i * 256 + t;
            int k = e >> 4, c4 = e & 15;
            *(float4*)&Bs[k][c4 * 4] = *(const float4*)&W[(size_t)(kt + k) * N + cbase + c4 * 4];
        }
        __syncthreads();
        #pragma unroll 8
        for (int k = 0; k < 64; ++k) {
            float2 av = *(const float2*)&As[k][ty * 2];
            float4 bv = *(const float4*)&Bs[k][tx * 4];
            acc[0][0] = fmaf(av.x, bv.x, acc[0][0]); acc[0][1] = fmaf(av.x, bv.y, acc[0][1]);
            acc[0][2] = fmaf(av.x, bv.z, acc[0][2]); acc[0][3] = fmaf(av.x, bv.w, acc[0][3]);
            acc[1][0] = fmaf(av.y, bv.x, acc[1][0]); acc[1][1] = fmaf(av.y, bv.y, acc[1][1]);
            acc[1][2] = fmaf(av.y, bv.z, acc[1][2]); acc[1][3] = fmaf(av.y, bv.w, acc[1][3]);
        }
        __syncthreads();
    }
    #pragma unroll
    for (int i = 0; i < 2; ++i) {
        int row = rbase + ty * 2 + i;
        #pragma unroll
        for (int j = 0; j < 4; ++j) {
            int col = cbase + tx * 4 + j;
            Y[(size_t)row * N + col] = fmaxf(acc[i][j] + bias[col], 0.f);
        }
    }
}

// ---------------- k1 final: ang[256][64] = normalize(X @ W[K=512][64] + b) ----------------
__global__ __launch_bounds__(256) void k1_final(
    const float* __restrict__ X, const float* __restrict__ W,
    const float* __restrict__ bias, float* __restrict__ ang)
{
    __shared__ __align__(16) float As[64][36];
    __shared__ __align__(16) float Bs[64][68];
    int t = threadIdx.x;
    int rbase = blockIdx.x * 32;
    int tx = t & 15, ty = t >> 4;
    float acc[2][4] = {};

    for (int kt = 0; kt < 512; kt += 64) {
        #pragma unroll
        for (int i = 0; i < 2; ++i) {
            int e = i * 256 + t;
            int r = e >> 4, k4 = e & 15;
            float4 v = *(const float4*)&X[(size_t)(rbase + r) * 512 + kt + k4 * 4];
            As[k4 * 4 + 0][r] = v.x; As[k4 * 4 + 1][r] = v.y;
            As[k4 * 4 + 2][r] = v.z; As[k4 * 4 + 3][r] = v.w;
        }
        #pragma unroll
        for (int i = 0; i < 4; ++i) {
            int e = i * 256 + t;
            int k = e >> 4, c4 = e & 15;
            *(float4*)&Bs[k][c4 * 4] = *(const float4*)&W[(size_t)(kt + k) * 64 + c4 * 4];
        }
        __syncthreads();
        #pragma unroll 8
        for (int k = 0; k < 64; ++k) {
            float2 av = *(const float2*)&As[k][ty * 2];
            float4 bv = *(const float4*)&Bs[k][tx * 4];
            acc[0][0] = fmaf(av.x, bv.x, acc[0][0]); acc[0][1] = fmaf(av.x, bv.y, acc[0][1]);
            acc[0][2] = fmaf(av.x, bv.z, acc[0][2]); acc[0][3] = fmaf(av.x, bv.w, acc[0][3]);
            acc[1][0] = fmaf(av.y, bv.x, acc[1][0]); acc[1][1] = fmaf(av.y, bv.y, acc[1][1]);
            acc[1][2] = fmaf(av.y, bv.z, acc[1][2]); acc[1][3] = fmaf(av.y, bv.w, acc[1][3]);
        }
        __syncthreads();
    }
    #pragma unroll
    for (int i = 0; i < 2; ++i) {
        float v[4];
        float ss = 0.f;
        #pragma unroll
        for (int j = 0; j < 4; ++j) {
            v[j] = acc[i][j] + bias[tx * 4 + j];
            ss = fmaf(v[j], v[j], ss);
        }
        ss += __shfl_xor(ss, 1); ss += __shfl_xor(ss, 2);
        ss += __shfl_xor(ss, 4); ss += __shfl_xor(ss, 8);
        float inv = 1.0f / (sqrtf(ss) + 1e-5f);
        int row = rbase + ty * 2 + i;
        #pragma unroll
        for (int j = 0; j < 4; ++j)
            ang[(size_t)row * 64 + tx * 4 + j] = v[j] * inv;
    }
}

// ---------------- K2: logits[256][PN] = ang @ ap^T (f32 GEMM) ----------------
__global__ __launch_bounds__(256) void k2_logits(
    const float* __restrict__ ang, const float* __restrict__ ap,
    float* __restrict__ logits)
{
    __shared__ __align__(16) float As[64][68];
    __shared__ __align__(16) float Bs[64][68];
    int t = threadIdx.x;
    int cbase = blockIdx.x * 64;
    int rbase = blockIdx.y * 64;
    #pragma unroll
    for (int i = 0; i < 4; ++i) {
        int e = i * 256 + t;
        int r = e >> 4, k4 = e & 15;
        float4 v = *(const float4*)&ang[(rbase + r) * 64 + k4 * 4];
        As[k4 * 4 + 0][r] = v.x; As[k4 * 4 + 1][r] = v.y;
        As[k4 * 4 + 2][r] = v.z; As[k4 * 4 + 3][r] = v.w;
    }
    #pragma unroll
    for (int i = 0; i < 4; ++i) {
        int e = i * 256 + t;
        int c = e >> 4, k4 = e & 15;
        int gc = cbase + c;
        float4 v = make_float4(0.f, 0.f, 0.f, 0.f);
        if (gc < PN) v = *(const float4*)&ap[(size_t)gc * 64 + k4 * 4];
        Bs[k4 * 4 + 0][c] = v.x; Bs[k4 * 4 + 1][c] = v.y;
        Bs[k4 * 4 + 2][c] = v.z; Bs[k4 * 4 + 3][c] = v.w;
    }
    __syncthreads();
    int tx = t & 15, ty = t >> 4;
    float acc[4][4];
    #pragma unroll
    for (int i = 0; i < 4; ++i)
        #pragma unroll
        for (int j = 0; j < 4; ++j) acc[i][j] = 0.f;
    #pragma unroll 8
    for (int k = 0; k < 64; ++k) {
        float4 av = *(const float4*)&As[k][ty * 4];
        float4 bv = *(const float4*)&Bs[k][tx * 4];
        acc[0][0] = fmaf(av.x, bv.x, acc[0][0]); acc[0][1] = fmaf(av.x, bv.y, acc[0][1]);
        acc[0][2] = fmaf(av.x, bv.z, acc[0][2]); acc[0][3] = fmaf(av.x, bv.w, acc[0][3]);
        acc[1][0] = fmaf(av.y, bv.x, acc[1][0]); acc[1][1] = fmaf(av.y, bv.y, acc[1][1]);
        acc[1][2] = fmaf(av.y, bv.z, acc[1][2]); acc[1][3] = fmaf(av.y, bv.w, acc[1][3]);
        acc[2][0] = fmaf(av.z, bv.x, acc[2][0]); acc[2][1] = fmaf(av.z, bv.y, acc[2][1]);
        acc[2][2] = fmaf(av.z, bv.z, acc[2][2]); acc[2][3] = fmaf(av.z, bv.w, acc[2][3]);
        acc[3][0] = fmaf(av.w, bv.x, acc[3][0]); acc[3][1] = fmaf(av.w, bv.y, acc[3][1]);
        acc[3][2] = fmaf(av.w, bv.z, acc[3][2]); acc[3][3] = fmaf(av.w, bv.w, acc[3][3]);
    }
    int gc = cbase + tx * 4;
    if (gc < PN) {
        #pragma unroll
        for (int i = 0; i < 4; ++i) {
            int rr = rbase + ty * 4 + i;
            *(float4*)&logits[(size_t)rr * PN + gc] =
                make_float4(acc[i][0], acc[i][1], acc[i][2], acc[i][3]);
        }
    }
}

// ---------------- K3: per-row softmax-sum + exact top-128 ----------------
#define CAP 2048
__global__ __launch_bounds__(1024) void k3_topk(
    const float* __restrict__ logits, const int* __restrict__ nin,
    float* __restrict__ srted, int* __restrict__ sidx,
    float* __restrict__ maskp, float* __restrict__ nrp)
{
    __shared__ unsigned int hist[8192];
    __shared__ unsigned int chunks[256];
    __shared__ float wsum[16];
    __shared__ float s_inv;
    __shared__ int s_T;
    __shared__ unsigned int ccnt;
    __shared__ unsigned int ckey[CAP];
    __shared__ unsigned int cidx[CAP];
    __shared__ unsigned long long arr[CAP];

    int r = blockIdx.x;
    int t = threadIdx.x;
    const float4* row4 = (const float4*)(logits + (size_t)r * PN);
    for (int i = t; i < 8192; i += 1024) hist[i] = 0u;
    if (t == 0) ccnt = 0u;
    __syncthreads();

    float es = 0.f;
    for (int i = t; i < PN / 4; i += 1024) {
        float4 v = row4[i];
        es += expf(v.x) + expf(v.y) + expf(v.z) + expf(v.w);
        atomicAdd(&hist[sortkey(v.x) >> 19], 1u);
        atomicAdd(&hist[sortkey(v.y) >> 19], 1u);
        atomicAdd(&hist[sortkey(v.z) >> 19], 1u);
        atomicAdd(&hist[sortkey(v.w) >> 19], 1u);
    }
    #pragma unroll
    for (int off = 32; off > 0; off >>= 1) es += __shfl_xor(es, off);
    if ((t & 63) == 0) wsum[t >> 6] = es;
    __syncthreads();
    if (t == 0) {
        float s = 0.f;
        for (int i = 0; i < 16; ++i) s += wsum[i];
        s_inv = 1.0f / s;
    }
    if (t < 256) {
        unsigned int cs = 0u;
        for (int b = 0; b < 32; ++b) cs += hist[t * 32 + b];
        chunks[t] = cs;
    }
    __syncthreads();
    if (t == 0) {
        unsigned int cum = 0u; int T = 0;
        for (int ci = 255; ci >= 0; --ci) {
            if (cum + chunks[ci] >= 128u) {
                for (int bb = ci * 32 + 31; ; --bb) {
                    unsigned int h = hist[bb];
                    if (cum + h >= 128u) { T = bb; break; }
                    cum += h;
                }
                break;
            }
            cum += chunks[ci];
        }
        s_T = T;
    }
    __syncthreads();
    int T = s_T;
    for (int i = t; i < PN / 4; i += 1024) {
        float4 v = row4[i];
        unsigned int kk;
        kk = sortkey(v.x);
        if ((int)(kk >> 19) >= T) { unsigned int p = atomicAdd(&ccnt, 1u); if (p < CAP) { ckey[p] = kk; cidx[p] = 4 * i + 0; } }
        kk = sortkey(v.y);
        if ((int)(kk >> 19) >= T) { unsigned int p = atomicAdd(&ccnt, 1u); if (p < CAP) { ckey[p] = kk; cidx[p] = 4 * i + 1; } }
        kk = sortkey(v.z);
        if ((int)(kk >> 19) >= T) { unsigned int p = atomicAdd(&ccnt, 1u); if (p < CAP) { ckey[p] = kk; cidx[p] = 4 * i + 2; } }
        kk = sortkey(v.w);
        if ((int)(kk >> 19) >= T) { unsigned int p = atomicAdd(&ccnt, 1u); if (p < CAP) { ckey[p] = kk; cidx[p] = 4 * i + 3; } }
    }
    __syncthreads();
    int nc = (int)min(ccnt, (unsigned int)CAP);
    int P = 128;
    while (P < nc) P <<= 1;
    for (int i = t; i < P; i += 1024)
        arr[i] = (i < nc) ? ((((unsigned long long)ckey[i]) << 32) | (unsigned int)(~cidx[i])) : 0ull;
    __syncthreads();
    for (int kk = 2; kk <= P; kk <<= 1) {
        for (int j = kk >> 1; j > 0; j >>= 1) {
            for (int i = t; i < P; i += 1024) {
                int l = i ^ j;
                if (l > i) {
                    unsigned long long a = arr[i], b = arr[l];
                    bool up = ((i & kk) == 0);
                    if (up ? (a < b) : (a > b)) { arr[i] = b; arr[l] = a; }
                }
            }
            __syncthreads();
        }
    }
    int nr = nin[r]; nr = nr < 1 ? 1 : (nr > 128 ? 128 : nr);
    if (t < 128) {
        unsigned long long c = arr[t];
        unsigned int key = (unsigned int)(c >> 32);
        unsigned int idx = ~((unsigned int)c);
        unsigned int u = (key & 0x80000000u) ? (key ^ 0x80000000u) : ~key;
        float v = __uint_as_float(u);
        srted[r * 128 + t] = expf(v) * s_inv;
        sidx[r * 128 + t] = (int)idx;
        maskp[r * 128 + t] = (t < nr) ? 1.0f : 0.0f;
    }
    if (t == 0) nrp[r] = (float)nr;
}

// ---------------- combined W transpose+convert ----------------
__global__ __launch_bounds__(256) void k_wconv_all(
    const float* __restrict__ ow1, const float* __restrict__ ow2, const float* __restrict__ ow3,
    f16* __restrict__ W1t, f16* __restrict__ W2t, f16* __restrict__ W3t)
{
    int idx = blockIdx.x * 256 + threadIdx.x;
    if (idx < 262144) {                       // W1t [512][512]
        int n = idx >> 9, k = idx & 511;
        W1t[idx] = (f16)ow1[(size_t)k * 512 + n];
    } else if (idx < 393216) {                // W2t [256][512]
        int j = idx - 262144;
        int n = j >> 9, k = j & 511;
        W2t[j] = (f16)ow2[(size_t)k * 256 + n];
    } else {                                  // W3t [256][256]
        int j = idx - 393216;
        int n = j >> 8, k = j & 255;
        W3t[j] = (f16)ow3[(size_t)k * 256 + n];
    }
}

// ---------------- Build X1[32768][512] f16 = [alpha*sel+beta | latent] ----------------
__global__ __launch_bounds__(256) void k_buildx(
    const float* __restrict__ points, const float* __restrict__ latent,
    const float* __restrict__ srted, const int* __restrict__ sidx,
    const float* __restrict__ l1w, const float* __restrict__ l1b,
    const float* __restrict__ l2w, const float* __restrict__ l2b,
    f16* __restrict__ X1)
{
    __shared__ float s_s[16];
    __shared__ int s_pi[16];
    int t = threadIdx.x;
    int tok0 = blockIdx.x * 16;
    if (t < 16) {
        int token = tok0 + t;
        s_s[t] = 128.0f * srted[token];
        s_pi[t] = sidx[token];
    }
    __syncthreads();
    float w1 = l1w[t], b1 = l1b[t], w2 = l2w[t], b2 = l2b[t];
    for (int tt = 0; tt < 16; ++tt) {
        int token = tok0 + tt;
        int b = token >> 7;
        float s = s_s[tt];
        float p = points[(size_t)s_pi[tt] * 256 + t];
        float alpha = fmaf(s, w1, b1);
        float beta = fmaf(s, w2, b2);
        X1[(size_t)token * 512 + t] = (f16)fmaf(alpha, p, beta);
        X1[(size_t)token * 512 + 256 + t] = (f16)latent[b * 256 + t];
    }
}

// ---------------- f16 MFMA GEMM: C[M][N] = A[M][K] @ Bt[N][K]^T + bias ----------------
template<int RELU, int OUT_F16>
__global__ __launch_bounds__(256) void gemm_tn(
    const f16* __restrict__ A, const f16* __restrict__ Bt,
    const float* __restrict__ bias,
    f16* __restrict__ Cf16, float* __restrict__ Cf32,
    int N, int K)
{
    __shared__ __align__(16) f16 As[128 * 64];
    __shared__ __align__(16) f16 Bs[128 * 64];
    int tid = threadIdx.x;
    int lane = tid & 63, wave = tid >> 6;
    int brow = blockIdx.y * 128;
    int bcol = blockIdx.x * 128;
    int wr = wave >> 1, wc = wave & 1;

    f32x4 acc[4][4] = {};

    int b_off = tid * 16;
    int sr = b_off >> 7;
    int soff = b_off & 127;
    char* ldsA = (char*)As + wave * 1024;
    char* ldsB = (char*)Bs + wave * 1024;

    for (int kt = 0; kt < K; kt += 64) {
        #pragma unroll
        for (int c = 0; c < 4; ++c) {
            int r = sr + c * 32;
            const char* ga = (const char*)A + ((size_t)(brow + r) * K + kt) * 2 + soff;
            gload_lds16(ga, ldsA + c * 4096);
        }
        #pragma unroll
        for (int c = 0; c < 4; ++c) {
            int r = sr + c * 32;
            const char* gb = (const char*)Bt + ((size_t)(bcol + r) * K + kt) * 2 + soff;
            gload_lds16(gb, ldsB + c * 4096);
        }
        __syncthreads();
        #pragma unroll
        for (int ks = 0; ks < 2; ++ks) {
            f16x8 af[4], bf[4];
            int kk = ks * 32 + (lane >> 4) * 8;
            #pragma unroll
            for (int i = 0; i < 4; ++i) {
                int row = wr * 64 + i * 16 + (lane & 15);
                af[i] = *(const f16x8*)&As[row * 64 + kk];
                int col = wc * 64 + i * 16 + (lane & 15);
                bf[i] = *(const f16x8*)&Bs[col * 64 + kk];
            }
            #pragma unroll
            for (int i = 0; i < 4; ++i)
                #pragma unroll
                for (int j = 0; j < 4; ++j)
                    acc[i][j] = __builtin_amdgcn_mfma_f32_16x16x32_f16(af[i], bf[j], acc[i][j], 0, 0, 0);
        }
        __syncthreads();
    }

    #pragma unroll
    for (int i = 0; i < 4; ++i) {
        int row = brow + wr * 64 + i * 16 + (lane >> 4) * 4;
        #pragma unroll
        for (int j = 0; j < 4; ++j) {
            int col = bcol + wc * 64 + j * 16 + (lane & 15);
            float bz = bias[col];
            #pragma unroll
            for (int r2 = 0; r2 < 4; ++r2) {
                float v = acc[i][j][r2] + bz;
                if (RELU) v = fmaxf(v, 0.f);
                if (OUT_F16) Cf16[(size_t)(row + r2) * N + col] = (f16)v;
                else         Cf32[(size_t)(row + r2) * N + col] = v;
            }
        }
    }
}

extern "C" void kernel_launch(void* const* d_in, const int* in_sizes, int n_in,
                              void* d_out, int out_size, void* d_ws, size_t ws_size,
                              hipStream_t stream) {
    (void)in_sizes; (void)n_in; (void)out_size; (void)ws_size;
    const float* latent = (const float*)d_in[0];
    const int*   nin    = (const int*)d_in[1];
    const float* points = (const float*)d_in[2];
    const float* ap     = (const float*)d_in[3];
    const float* aw1 = (const float*)d_in[4];  const float* ab1 = (const float*)d_in[5];
    const float* aw2 = (const float*)d_in[6];  const float* ab2 = (const float*)d_in[7];
    const float* aw3 = (const float*)d_in[8];  const float* ab3 = (const float*)d_in[9];
    const float* aw4 = (const float*)d_in[10]; const float* ab4 = (const float*)d_in[11];
    const float* l1w = (const float*)d_in[12]; const float* l1b = (const float*)d_in[13];
    const float* l2w = (const float*)d_in[14]; const float* l2b = (const float*)d_in[15];
    const float* ow1 = (const float*)d_in[16]; const float* ob1 = (const float*)d_in[17];
    const float* ow2 = (const float*)d_in[18]; const float* ob2 = (const float*)d_in[19];
    const float* ow3 = (const float*)d_in[20]; const float* ob3 = (const float*)d_in[21];

    char* wsb = (char*)d_ws;
    float* ang   = (float*)wsb;                 // 64 KB
    float* srted = (float*)(wsb + 65536);       // 128 KB
    int*   sidx  = (int*)(wsb + 196608);        // 128 KB
    float* logit = (float*)(wsb + 327680);      // 102.4 MB

    // dead-logit region reuse:
    char* lz = wsb + 327680;
    // phase A (before k2): angle-MLP hidden buffers
    float* h1 = (float*)lz;                     // 512 KB [256][512]
    float* h2 = (float*)(lz + 524288);          // 512 KB
    float* h3 = (float*)(lz + 1048576);         // 512 KB
    // phase B (after k3): final-MLP buffers
    f16* X1  = (f16*)lz;                        // 32 MB
    f16* H1  = (f16*)(lz + 33554432);           // 32 MB
    f16* H2  = (f16*)(lz + 67108864);           // 16 MB
    f16* W1t = (f16*)(lz + 83886080);           // 512 KB [512][512]
    f16* W2t = (f16*)(lz + 84410368);           // 256 KB [256][512]
    f16* W3t = (f16*)(lz + 84672512);           // 128 KB [256][256]

    float* outp  = (float*)d_out;               // [32768][256]
    float* maskp = outp + 8388608;              // [256][128]
    float* nrp   = outp + 8421376;              // [256]

    hipLaunchKernelGGL(k1_layer, dim3(8, 8), dim3(256), 0, stream, latent, aw1, ab1, h1, 512, 256);
    hipLaunchKernelGGL(k1_layer, dim3(8, 8), dim3(256), 0, stream, h1, aw2, ab2, h2, 512, 512);
    hipLaunchKernelGGL(k1_layer, dim3(8, 8), dim3(256), 0, stream, h2, aw3, ab3, h3, 512, 512);
    hipLaunchKernelGGL(k1_final, dim3(8), dim3(256), 0, stream, h3, aw4, ab4, ang);
    hipLaunchKernelGGL(k2_logits, dim3((PN + 63) / 64, 4), dim3(256), 0, stream,
                       ang, ap, logit);
    hipLaunchKernelGGL(k3_topk, dim3(256), dim3(1024), 0, stream,
                       logit, nin, srted, sidx, maskp, nrp);
    hipLaunchKernelGGL(k_wconv_all, dim3(1792), dim3(256), 0, stream, ow1, ow2, ow3, W1t, W2t, W3t);
    hipLaunchKernelGGL(k_buildx, dim3(2048), dim3(256), 0, stream,
                       points, latent, srted, sidx, l1w, l1b, l2w, l2b, X1);
    hipLaunchKernelGGL((gemm_tn<1, 1>), dim3(4, 256), dim3(256), 0, stream,
                       X1, W1t, ob1, H1, (float*)nullptr, 512, 512);
    hipLaunchKernelGGL((gemm_tn<1, 1>), dim3(2, 256), dim3(256), 0, stream,
                       H1, W2t, ob2, H2, (float*)nullptr, 256, 512);
    hipLaunchKernelGGL((gemm_tn<0, 0>), dim3(2, 256), dim3(256), 0, stream,
                       H2, W3t, ob3, (f16*)nullptr, outp, 256, 256);
}